// Round 16
// baseline (214.377 us; speedup 1.0000x reference)
//
#include <hip/hip_runtime.h>
#include <math.h>

#define NN   8192
#define EE   262144
#define CIN  64
#define DD   192      // IN_C*K = OUT_C*K
#define GG   64
#define NCLS 10
#define D3   576      // 3*DD
#define F1   384
#define F2   192
#define EPSB 1e-5f
#define NB   64        // edge-chunk blocks for count/scatter
#define EPB  (EE / NB) // 4096 edges per block
#define PS   8         // pool splits per graph

// ---- pack (0..323) + sigma (324) + gstart (325) + edge histogram (326..389)
__global__ __launch_bounds__(1024) void prep_kernel(const float* __restrict__ W,
    const float* __restrict__ u, const float* __restrict__ w1,
    const float* __restrict__ w2, const int* __restrict__ batch,
    const int* __restrict__ ei,
    float* __restrict__ sig, int* __restrict__ gstart, int* __restrict__ pcnt,
    float* __restrict__ Wp, float* __restrict__ Wp1, float* __restrict__ Wp2) {
    __shared__ int hist[NN];            // count blocks; aliased by sigma block
    int b = blockIdx.x, t = threadIdx.x;
    if (b < 324) {                      // ---- weight pack ----
        int idx = b * 1024 + t;
        if (idx < DD * DD) {
            int r = idx / DD, c = idx - r * DD;      // W element (out r, in c)
            float m = (c < CIN * ((r >> 6) + 1)) ? 1.f : 0.f;
            Wp[((c >> 2) * DD + r) * 4 + (c & 3)] = m * W[idx];
        } else if (idx < DD * DD + F1 * D3) {
            int i1 = idx - DD * DD;
            int tt = i1 / D3, k = i1 - tt * D3;
            Wp1[((k >> 2) * F1 + tt) * 4 + (k & 3)] = w1[i1];
        } else {
            int i2 = idx - DD * DD - F1 * D3;
            int tt = i2 / F1, k = i2 - tt * F1;
            Wp2[((k >> 2) * F2 + tt) * 4 + (k & 3)] = w2[i2];
        }
        return;
    }
    if (b == 325) {                     // ---- gstart (sorted-batch bounds) ----
        for (int i = t; i < NN; i += 1024) {
            int b0 = batch[i];
            int b1 = (i + 1 < NN) ? batch[i + 1] : GG;
            if (i == 0) { for (int g = 0; g <= b0; g++) gstart[g] = 0; }
            for (int g = b0 + 1; g <= b1; g++) gstart[g] = i + 1;
        }
        return;
    }
    if (b >= 326) {                     // ---- per-chunk edge histogram ----
        int cb = b - 326;               // chunk id 0..NB-1
        int4* hz = (int4*)hist;
        for (int i = t; i < NN / 4; i += 1024) hz[i] = make_int4(0, 0, 0, 0);
        __syncthreads();
        int e0 = cb * EPB;
        for (int i = t; i < EPB; i += 1024) atomicAdd(&hist[ei[e0 + i]], 1);
        __syncthreads();
        const int4* hs = (const int4*)hist;
        int4* p4 = (int4*)&pcnt[cb * NN];
        for (int i = t; i < NN / 4; i += 1024) p4[i] = hs[i];
        return;
    }
    // ---- sigma (block 324; LDS aliases hist) ----
    float* vp  = (float*)hist;          // 768 floats
    float* vsh = vp + 768;              // 192 floats
    float* red = vsh + DD;              // 1024 floats (total 7.75 KB < 32 KB)
    if (t < 768) {
        int c = t >> 2, j = t & 3;
        float s = 0.f;
        const float* Wc = W + c;
        for (int i = j * 48; i < j * 48 + 48; i++) s += Wc[i * DD] * u[i];
        vp[t] = s;
    }
    __syncthreads();
    float vv = 0.f;
    if (t < DD) {
        float v = vp[4 * t] + vp[4 * t + 1] + vp[4 * t + 2] + vp[4 * t + 3];
        vsh[t] = v;
        vv = v * v;
    }
    red[t] = vv;
    __syncthreads();
    for (int off = 512; off > 0; off >>= 1) {
        if (t < off) red[t] += red[t + off];
        __syncthreads();
    }
    float norm = sqrtf(red[0]) + 1e-12f;
    __syncthreads();
    float a = 0.f;
    for (int idx = t; idx < DD * DD; idx += 1024) {
        int r = idx / DD, c = idx - r * DD;
        a += u[r] * W[idx] * vsh[c];
    }
    red[t] = a;
    __syncthreads();
    for (int off = 512; off > 0; off >>= 1) {
        if (t < off) red[t] += red[t + off];
        __syncthreads();
    }
    if (t == 0) sig[0] = norm / red[0];      // inv_sigma = norm / S
}

// ---- CSR build, self-contained: stream pcnt -> deg/off in regs,
//      LDS scan -> cursors; block 0 publishes rowptr + dinv ----
__global__ __launch_bounds__(1024) void scatter_kernel(const int* __restrict__ ei,
                                                       const int* __restrict__ pcnt,
                                                       int* __restrict__ rowptr,
                                                       float* __restrict__ dinv,
                                                       unsigned short* __restrict__ csr_col) {
    __shared__ int cur[NN];
    __shared__ int temp[1024];
    int b = blockIdx.x, t = threadIdx.x;
    int base = t * 8;                   // this thread's 8 contiguous rows
    int d[8] = {0,0,0,0,0,0,0,0};
    int of[8] = {0,0,0,0,0,0,0,0};
    for (int bb = 0; bb < NB; bb++) {
        const int4 a4 = *(const int4*)&pcnt[bb * NN + base];      // coalesced
        const int4 b4 = *(const int4*)&pcnt[bb * NN + base + 4];
        if (bb < b) {
            of[0] += a4.x; of[1] += a4.y; of[2] += a4.z; of[3] += a4.w;
            of[4] += b4.x; of[5] += b4.y; of[6] += b4.z; of[7] += b4.w;
        }
        d[0] += a4.x; d[1] += a4.y; d[2] += a4.z; d[3] += a4.w;
        d[4] += b4.x; d[5] += b4.y; d[6] += b4.z; d[7] += b4.w;
    }
    int l[8];
    int run = 0;
#pragma unroll
    for (int j = 0; j < 8; j++) { l[j] = run; run += d[j]; }
    temp[t] = run;
    __syncthreads();
    for (int o = 1; o < 1024; o <<= 1) {
        int v = (t >= o) ? temp[t - o] : 0;
        __syncthreads();
        temp[t] += v;
        __syncthreads();
    }
    int prefix = (t > 0) ? temp[t - 1] : 0;
#pragma unroll
    for (int j = 0; j < 8; j++) cur[base + j] = prefix + l[j] + of[j];
    if (b == 0) {
#pragma unroll
        for (int j = 0; j < 8; j++) {
            rowptr[base + j] = prefix + l[j];
            dinv[base + j] = (d[j] > 0) ? rsqrtf((float)d[j]) : 0.f;
        }
        if (t == 1023) rowptr[NN] = temp[1023];
    }
    __syncthreads();
    int e0 = b * EPB;
    for (int i = t; i < EPB; i += 1024) {
        int r = ei[e0 + i];
        int c = ei[EE + e0 + i];
        int pos = atomicAdd(&cur[r], 1);       // LDS atomic
        csr_col[pos] = (unsigned short)c;
    }
}

// 64 lanes per row (one wave = one row), 2-way unrolled edge loop.
// out = h_row - dinv[row] * sum_e dinv[col_e] * h[col_e]
__global__ __launch_bounds__(256) void spmm_kernel(const float* __restrict__ hin,
    int in_stride, int in_off,
    const int* __restrict__ rowptr, const unsigned short* __restrict__ col,
    const float* __restrict__ dinv,
    float* __restrict__ Hcat, int coff, int write_self) {
    int idx = blockIdx.x * 256 + threadIdx.x;   // N*64 threads
    int row = idx >> 6;
    int lane = idx & 63;
    int s = rowptr[row], e = rowptr[row + 1];
    float acc0 = 0.f, acc1 = 0.f;
    int p = s;
    for (; p + 1 < e; p += 2) {
        int c0 = col[p], c1 = col[p + 1];
        acc0 += dinv[c0] * hin[c0 * in_stride + in_off + lane];
        acc1 += dinv[c1] * hin[c1 * in_stride + in_off + lane];
    }
    if (p < e) {
        int c = col[p];
        acc0 += dinv[c] * hin[c * in_stride + in_off + lane];
    }
    float acc = acc0 + acc1;
    float self = hin[row * in_stride + in_off + lane];
    Hcat[row * DD + coff + lane] = self - dinv[row] * acc;
    if (write_self) Hcat[row * DD + lane] = self;
}

// ------ H = inv_sigma * (Hcat @ Wmask^T) + b, IN PLACE, 16 rows/block -------
__global__ __launch_bounds__(192) void gemm_kernel(float* __restrict__ Hcat,
    const float* __restrict__ Wp, const float* __restrict__ bias,
    const float* __restrict__ sig) {
    __shared__ float hs[16 * DD];
    int t = threadIdx.x;          // t = output channel
    int n0 = blockIdx.x * 16;
    const float4* src = (const float4*)&Hcat[n0 * DD];   // 768 float4s
    float4* dst = (float4*)hs;
#pragma unroll
    for (int i = 0; i < 4; i++) dst[t + 192 * i] = src[t + 192 * i];
    __syncthreads();
    float acc[16];
#pragma unroll
    for (int r = 0; r < 16; r++) acc[r] = 0.f;
    const float4* Wp4 = (const float4*)Wp;
    for (int k4 = 0; k4 < DD / 4; k4++) {
        float4 w = Wp4[k4 * DD + t];
#pragma unroll
        for (int r = 0; r < 16; r++) {
            const float4 h = *(const float4*)&hs[r * DD + k4 * 4];
            acc[r] += h.x * w.x + h.y * w.y + h.z * w.z + h.w * w.w;
        }
    }
    float inv_sigma = sig[0];
    float bv = bias[t];
#pragma unroll
    for (int r = 0; r < 16; r++) Hcat[(n0 + r) * DD + t] = inv_sigma * acc[r] + bv;
}

// ------ raw per-graph pooling partials: 8 split-blocks per graph ------------
__global__ __launch_bounds__(192) void pool_kernel(const float* __restrict__ H,
    const int* __restrict__ gstart,
    float* __restrict__ Psum, float* __restrict__ Psq,
    float* __restrict__ Pmin, float* __restrict__ Pmax) {
    int b = blockIdx.x;              // grid = GG*PS
    int g = b >> 3, s = b & 7, c = threadIdx.x;
    int beg = gstart[g], end = gstart[g + 1];
    float sum = 0.f, sq = 0.f, mn = INFINITY, mx = -INFINITY;
    for (int i = beg + s; i < end; i += PS) {
        float x = H[i * DD + c];
        sum += x; sq += x * x;
        mn = fminf(mn, x); mx = fmaxf(mx, x);
    }
    Psum[b * DD + c] = sum; Psq[b * DD + c] = sq;
    Pmin[b * DD + c] = mn;  Pmax[b * DD + c] = mx;
}

// ------ BN1 finalize (fused, butterfly) + Hg + BN2: block=column, lane=graph
__global__ __launch_bounds__(64) void hg_kernel(
    const float* __restrict__ Psum, const float* __restrict__ Psq,
    const float* __restrict__ Pmin, const float* __restrict__ Pmax,
    const int* __restrict__ gstart,
    const float* __restrict__ g1, const float* __restrict__ be1,
    const float* __restrict__ g2, const float* __restrict__ be2,
    float* __restrict__ Hg) {
    int t = blockIdx.x;          // column 0..D3-1
    int g = threadIdx.x;         // graph 0..63
    int f = t / DD, c = t - f * DD;  // f: 0=avg 1=sum 2=max (block-uniform)
    float Sg = 0.f, Qg = 0.f;
#pragma unroll
    for (int s = 0; s < PS; s++) {
        Sg += Psum[(g * PS + s) * DD + c];
        Qg += Psq[(g * PS + s) * DD + c];
    }
    float S = Sg, Q = Qg;
    for (int off = 32; off > 0; off >>= 1) {
        S += __shfl_xor(S, off);
        Q += __shfl_xor(Q, off);
    }
    float mu = S * (1.f / (float)NN);
    float var = Q * (1.f / (float)NN) - mu * mu;
    float sc = g1[c] * rsqrtf(var + EPSB);
    float bb = be1[c];
    float v;
    if (f == 2) {
        float mx = -INFINITY, mn = INFINITY;
#pragma unroll
        for (int s = 0; s < PS; s++) {
            mx = fmaxf(mx, Pmax[(g * PS + s) * DD + c]);
            mn = fminf(mn, Pmin[(g * PS + s) * DD + c]);
        }
        float raw = (sc >= 0.f) ? mx : mn;
        v = sc * (raw - mu) + bb;
    } else {
        float nf = (float)(gstart[g + 1] - gstart[g]);
        float hsum = sc * (Sg - nf * mu) + nf * bb;
        v = (f == 0) ? hsum / fmaxf(nf, 1.f) : hsum;
    }
    float s2 = v, ss2 = v * v;
    for (int off = 32; off > 0; off >>= 1) {
        s2 += __shfl_xor(s2, off);
        ss2 += __shfl_xor(ss2, off);
    }
    float m2 = s2 * (1.f / (float)GG);
    float var2 = ss2 * (1.f / (float)GG) - m2 * m2;
    float sc2 = g2[t] * rsqrtf(var2 + EPSB);
    Hg[g * D3 + t] = sc2 * (v - m2) + be2[t];
}

// ------ funnel head + log_softmax, ONE graph per block (64 blocks) ----------
__global__ __launch_bounds__(F1) void funnel_kernel(const float* __restrict__ Hg,
    const float* __restrict__ Wp1, const float* __restrict__ b1,
    const float* __restrict__ Wp2, const float* __restrict__ b2,
    const float* __restrict__ w3, const float* __restrict__ b3,
    float* __restrict__ out) {
    __shared__ float hg[D3];
    __shared__ float x1[F1];
    __shared__ float x2[F2];
    __shared__ float lg[NCLS];
    __shared__ float s_lse;
    int g = blockIdx.x, t = threadIdx.x;
    for (int i = t; i < D3; i += F1) hg[i] = Hg[g * D3 + i];
    __syncthreads();
    {
        float a = b1[t];
        const float4* W4 = (const float4*)Wp1;
        for (int k4 = 0; k4 < D3 / 4; k4++) {
            float4 w = W4[k4 * F1 + t];                 // coalesced
            const float4 h = *(const float4*)&hg[k4 * 4]; // broadcast
            a += w.x * h.x + w.y * h.y + w.z * h.z + w.w * h.w;
        }
        x1[t] = fmaxf(a, 0.f);
    }
    __syncthreads();
    if (t < F2) {
        float a = b2[t];
        const float4* W4 = (const float4*)Wp2;
        for (int k4 = 0; k4 < F1 / 4; k4++) {
            float4 w = W4[k4 * F2 + t];                 // coalesced
            const float4 h = *(const float4*)&x1[k4 * 4]; // broadcast
            a += w.x * h.x + w.y * h.y + w.z * h.z + w.w * h.w;
        }
        x2[t] = fmaxf(a, 0.f);
    }
    __syncthreads();
    if (t < NCLS) {
        float a = b3[t];
        const float4* wr = (const float4*)&w3[t * F2];
        const float4* h4 = (const float4*)x2;
        for (int k = 0; k < F2 / 4; k++) {
            float4 w = wr[k], h = h4[k];
            a += w.x * h.x + w.y * h.y + w.z * h.z + w.w * h.w;
        }
        lg[t] = a;
    }
    __syncthreads();
    if (t == 0) {
        float m = lg[0];
        for (int i = 1; i < NCLS; i++) m = fmaxf(m, lg[i]);
        float se = 0.f;
        for (int i = 0; i < NCLS; i++) se += expf(lg[i] - m);
        s_lse = m + logf(se);
    }
    __syncthreads();
    if (t < NCLS) out[g * NCLS + t] = lg[t] - s_lse;
}

// ---------------- launcher ----------------

extern "C" void kernel_launch(void* const* d_in, const int* in_sizes, int n_in,
                              void* d_out, int out_size, void* d_ws, size_t ws_size,
                              hipStream_t stream) {
    (void)in_sizes; (void)n_in; (void)out_size; (void)ws_size;
    const float* x     = (const float*)d_in[0];
    const int*   ei    = (const int*)d_in[1];    // int32 on device (harness contract)
    const int*   batch = (const int*)d_in[2];
    const float* W     = (const float*)d_in[3];
    const float* b     = (const float*)d_in[4];
    const float* u     = (const float*)d_in[5];
    const float* g1    = (const float*)d_in[6];
    const float* be1   = (const float*)d_in[7];
    const float* g2    = (const float*)d_in[8];
    const float* be2   = (const float*)d_in[9];
    const float* w1    = (const float*)d_in[10];
    const float* b1    = (const float*)d_in[11];
    const float* w2    = (const float*)d_in[12];
    const float* b2    = (const float*)d_in[13];
    const float* w3    = (const float*)d_in[14];
    const float* b3    = (const float*)d_in[15];
    float* out = (float*)d_out;
    char*  ws  = (char*)d_ws;

    // ---- workspace layout (bytes), ~12 MB ----
    int*            gstart  = (int*)(ws + 0);            //     512 (65 ints)
    int*            rowptr  = (int*)(ws + 512);          //   33024
    float*          dinv    = (float*)(ws + 66304);      //   32768
    float*          sig     = (float*)(ws + 99072);      //     256
    float*          Wp      = (float*)(ws + 99328);      //  147456
    float*          Psum    = (float*)(ws + 246784);     //  393216 (GG*PS*DD)
    float*          Psq     = (float*)(ws + 640000);     //  393216
    float*          Pmin    = (float*)(ws + 1033216);    //  393216
    float*          Pmax    = (float*)(ws + 1426432);    //  393216
    float*          Hg      = (float*)(ws + 1819648);    //  147456
    unsigned short* csr_col = (unsigned short*)(ws + 1967104); // 524288
    float*          Wp1     = (float*)(ws + 2491392);    //  884736
    float*          Wp2     = (float*)(ws + 3376128);    //  294912
    int*            pcnt    = (int*)(ws + 3671040);      // 2097152
    float*          Hcat    = (float*)(ws + 5768192);    // 6291456 -> end 12059648

    prep_kernel<<<326 + NB, 1024, 0, stream>>>(W, u, w1, w2, batch, ei,
                                               sig, gstart, pcnt, Wp, Wp1, Wp2);
    scatter_kernel<<<NB, 1024, 0, stream>>>(ei, pcnt, rowptr, dinv, csr_col);
    // pass 1: read x [N,64], write Hcat col-block 1 (+ copy x into col-block 0)
    spmm_kernel<<<NN * 64 / 256, 256, 0, stream>>>(x, CIN, 0, rowptr, csr_col, dinv, Hcat, CIN, 1);
    // pass 2: read Hcat col-block 1 (strided), write Hcat col-block 2
    spmm_kernel<<<NN * 64 / 256, 256, 0, stream>>>(Hcat, DD, CIN, rowptr, csr_col, dinv, Hcat, 2 * CIN, 0);
    gemm_kernel<<<NN / 16, 192, 0, stream>>>(Hcat, Wp, b, sig);
    pool_kernel<<<GG * PS, 192, 0, stream>>>(Hcat, gstart, Psum, Psq, Pmin, Pmax);
    hg_kernel<<<D3, 64, 0, stream>>>(Psum, Psq, Pmin, Pmax, gstart, g1, be1, g2, be2, Hg);
    funnel_kernel<<<GG, F1, 0, stream>>>(Hg, Wp1, b1, Wp2, b2, w3, b3, out);
}

// Round 17
// 198.525 us; speedup vs baseline: 1.0799x; 1.0799x over previous
//
#include <hip/hip_runtime.h>
#include <math.h>

#define NN   8192
#define EE   262144
#define CIN  64
#define DD   192      // IN_C*K = OUT_C*K
#define GG   64
#define NCLS 10
#define D3   576      // 3*DD
#define F1   384
#define F2   192
#define EPSB 1e-5f
#define NB   64        // edge-chunk blocks for count/scatter
#define EPB  (EE / NB) // 4096 edges per block
#define PS   8         // pool splits per graph

// ---- pack (0..323) + sigma (324) + gstart (325) + edge histogram (326..389)
__global__ __launch_bounds__(1024) void prep_kernel(const float* __restrict__ W,
    const float* __restrict__ u, const float* __restrict__ w1,
    const float* __restrict__ w2, const int* __restrict__ batch,
    const int* __restrict__ ei,
    float* __restrict__ sig, int* __restrict__ gstart, int* __restrict__ pcnt,
    float* __restrict__ Wp, float* __restrict__ Wp1, float* __restrict__ Wp2) {
    __shared__ int hist[NN];            // count blocks; aliased by sigma block
    int b = blockIdx.x, t = threadIdx.x;
    if (b < 324) {                      // ---- weight pack ----
        int idx = b * 1024 + t;
        if (idx < DD * DD) {
            int r = idx / DD, c = idx - r * DD;      // W element (out r, in c)
            float m = (c < CIN * ((r >> 6) + 1)) ? 1.f : 0.f;
            Wp[((c >> 2) * DD + r) * 4 + (c & 3)] = m * W[idx];
        } else if (idx < DD * DD + F1 * D3) {
            int i1 = idx - DD * DD;
            int tt = i1 / D3, k = i1 - tt * D3;
            Wp1[((k >> 2) * F1 + tt) * 4 + (k & 3)] = w1[i1];
        } else {
            int i2 = idx - DD * DD - F1 * D3;
            int tt = i2 / F1, k = i2 - tt * F1;
            Wp2[((k >> 2) * F2 + tt) * 4 + (k & 3)] = w2[i2];
        }
        return;
    }
    if (b == 325) {                     // ---- gstart (sorted-batch bounds) ----
        for (int i = t; i < NN; i += 1024) {
            int b0 = batch[i];
            int b1 = (i + 1 < NN) ? batch[i + 1] : GG;
            if (i == 0) { for (int g = 0; g <= b0; g++) gstart[g] = 0; }
            for (int g = b0 + 1; g <= b1; g++) gstart[g] = i + 1;
        }
        return;
    }
    if (b >= 326) {                     // ---- per-chunk edge histogram ----
        int cb = b - 326;               // chunk id 0..NB-1
        int4* hz = (int4*)hist;
        for (int i = t; i < NN / 4; i += 1024) hz[i] = make_int4(0, 0, 0, 0);
        __syncthreads();
        int e0 = cb * EPB;
        for (int i = t; i < EPB; i += 1024) atomicAdd(&hist[ei[e0 + i]], 1);
        __syncthreads();
        const int4* hs = (const int4*)hist;
        int4* p4 = (int4*)&pcnt[cb * NN];
        for (int i = t; i < NN / 4; i += 1024) p4[i] = hs[i];
        return;
    }
    // ---- sigma (block 324; LDS aliases hist) ----
    float* vp  = (float*)hist;          // 768 floats
    float* vsh = vp + 768;              // 192 floats
    float* red = vsh + DD;              // 1024 floats
    if (t < 768) {
        int c = t >> 2, j = t & 3;
        float s = 0.f;
        const float* Wc = W + c;
        for (int i = j * 48; i < j * 48 + 48; i++) s += Wc[i * DD] * u[i];
        vp[t] = s;
    }
    __syncthreads();
    float vv = 0.f;
    if (t < DD) {
        float v = vp[4 * t] + vp[4 * t + 1] + vp[4 * t + 2] + vp[4 * t + 3];
        vsh[t] = v;
        vv = v * v;
    }
    red[t] = vv;
    __syncthreads();
    for (int off = 512; off > 0; off >>= 1) {
        if (t < off) red[t] += red[t + off];
        __syncthreads();
    }
    float norm = sqrtf(red[0]) + 1e-12f;
    __syncthreads();
    float a = 0.f;
    for (int idx = t; idx < DD * DD; idx += 1024) {
        int r = idx / DD, c = idx - r * DD;
        a += u[r] * W[idx] * vsh[c];
    }
    red[t] = a;
    __syncthreads();
    for (int off = 512; off > 0; off >>= 1) {
        if (t < off) red[t] += red[t + off];
        __syncthreads();
    }
    if (t == 0) sig[0] = norm / red[0];      // inv_sigma = norm / S
}

// ---- per-row reduce + exclusive scan over blocks: off[b][i], deg[i], dinv[i]
__global__ __launch_bounds__(256) void offs_kernel(int* __restrict__ pcnt,
                                                   int* __restrict__ deg,
                                                   float* __restrict__ dinv) {
    int i = blockIdx.x * 256 + threadIdx.x;   // grid = NN/256
    int run = 0;
#pragma unroll
    for (int b = 0; b < NB; b++) {
        int v = pcnt[b * NN + i];
        pcnt[b * NN + i] = run;               // becomes off[b][i]
        run += v;
    }
    deg[i] = run;
    dinv[i] = (run > 0) ? rsqrtf((float)run) : 0.f;
}

// ---- CSR build: per-block LDS scan of deg -> cursors; block 0 -> rowptr ----
__global__ __launch_bounds__(1024) void scatter_kernel(const int* __restrict__ ei,
                                                       const int* __restrict__ deg,
                                                       const int* __restrict__ off,
                                                       int* __restrict__ rowptr,
                                                       unsigned short* __restrict__ csr_col) {
    __shared__ int cur[NN];
    __shared__ int temp[1024];
    int b = blockIdx.x, t = threadIdx.x;
    int base = t * 8;
    int d[8], l[8];
    {
        const int4 a4 = *(const int4*)&deg[base];
        const int4 b4 = *(const int4*)&deg[base + 4];
        d[0] = a4.x; d[1] = a4.y; d[2] = a4.z; d[3] = a4.w;
        d[4] = b4.x; d[5] = b4.y; d[6] = b4.z; d[7] = b4.w;
    }
    int run = 0;
#pragma unroll
    for (int j = 0; j < 8; j++) { l[j] = run; run += d[j]; }
    temp[t] = run;
    __syncthreads();
    for (int o = 1; o < 1024; o <<= 1) {
        int v = (t >= o) ? temp[t - o] : 0;
        __syncthreads();
        temp[t] += v;
        __syncthreads();
    }
    int prefix = (t > 0) ? temp[t - 1] : 0;
    const int* ob = &off[b * NN];
#pragma unroll
    for (int j = 0; j < 8; j++) cur[base + j] = prefix + l[j] + ob[base + j];
    if (b == 0) {
#pragma unroll
        for (int j = 0; j < 8; j++) rowptr[base + j] = prefix + l[j];
        if (t == 1023) rowptr[NN] = temp[1023];
    }
    __syncthreads();
    int e0 = b * EPB;
    for (int i = t; i < EPB; i += 1024) {
        int r = ei[e0 + i];
        int c = ei[EE + e0 + i];
        int pos = atomicAdd(&cur[r], 1);       // LDS atomic
        csr_col[pos] = (unsigned short)c;
    }
}

// 64 lanes per row (one wave = one row), 2-way unrolled edge loop.
// out = h_row - dinv[row] * sum_e dinv[col_e] * h[col_e]
__global__ __launch_bounds__(256) void spmm_kernel(const float* __restrict__ hin,
    int in_stride, int in_off,
    const int* __restrict__ rowptr, const unsigned short* __restrict__ col,
    const float* __restrict__ dinv,
    float* __restrict__ Hcat, int coff, int write_self) {
    int idx = blockIdx.x * 256 + threadIdx.x;   // N*64 threads
    int row = idx >> 6;
    int lane = idx & 63;
    int s = rowptr[row], e = rowptr[row + 1];
    float acc0 = 0.f, acc1 = 0.f;
    int p = s;
    for (; p + 1 < e; p += 2) {
        int c0 = col[p], c1 = col[p + 1];
        acc0 += dinv[c0] * hin[c0 * in_stride + in_off + lane];
        acc1 += dinv[c1] * hin[c1 * in_stride + in_off + lane];
    }
    if (p < e) {
        int c = col[p];
        acc0 += dinv[c] * hin[c * in_stride + in_off + lane];
    }
    float acc = acc0 + acc1;
    float self = hin[row * in_stride + in_off + lane];
    Hcat[row * DD + coff + lane] = self - dinv[row] * acc;
    if (write_self) Hcat[row * DD + lane] = self;
}

// ------ H = inv_sigma * (Hcat @ Wmask^T) + b, IN PLACE, 16 rows/block -------
__global__ __launch_bounds__(192) void gemm_kernel(float* __restrict__ Hcat,
    const float* __restrict__ Wp, const float* __restrict__ bias,
    const float* __restrict__ sig) {
    __shared__ float hs[16 * DD];
    int t = threadIdx.x;          // t = output channel
    int n0 = blockIdx.x * 16;
    const float4* src = (const float4*)&Hcat[n0 * DD];   // 768 float4s
    float4* dst = (float4*)hs;
#pragma unroll
    for (int i = 0; i < 4; i++) dst[t + 192 * i] = src[t + 192 * i];
    __syncthreads();
    float acc[16];
#pragma unroll
    for (int r = 0; r < 16; r++) acc[r] = 0.f;
    const float4* Wp4 = (const float4*)Wp;
    for (int k4 = 0; k4 < DD / 4; k4++) {
        float4 w = Wp4[k4 * DD + t];
#pragma unroll
        for (int r = 0; r < 16; r++) {
            const float4 h = *(const float4*)&hs[r * DD + k4 * 4];
            acc[r] += h.x * w.x + h.y * w.y + h.z * w.z + h.w * w.w;
        }
    }
    float inv_sigma = sig[0];
    float bv = bias[t];
#pragma unroll
    for (int r = 0; r < 16; r++) Hcat[(n0 + r) * DD + t] = inv_sigma * acc[r] + bv;
}

// ------ raw per-graph pooling partials: 8 split-blocks per graph ------------
__global__ __launch_bounds__(192) void pool_kernel(const float* __restrict__ H,
    const int* __restrict__ gstart,
    float* __restrict__ Psum, float* __restrict__ Psq,
    float* __restrict__ Pmin, float* __restrict__ Pmax) {
    int b = blockIdx.x;              // grid = GG*PS
    int g = b >> 3, s = b & 7, c = threadIdx.x;
    int beg = gstart[g], end = gstart[g + 1];
    float sum = 0.f, sq = 0.f, mn = INFINITY, mx = -INFINITY;
    for (int i = beg + s; i < end; i += PS) {
        float x = H[i * DD + c];
        sum += x; sq += x * x;
        mn = fminf(mn, x); mx = fmaxf(mx, x);
    }
    Psum[b * DD + c] = sum; Psq[b * DD + c] = sq;
    Pmin[b * DD + c] = mn;  Pmax[b * DD + c] = mx;
}

// ------ BN1 finalize (fused, butterfly) + Hg + BN2: block=column, lane=graph
__global__ __launch_bounds__(64) void hg_kernel(
    const float* __restrict__ Psum, const float* __restrict__ Psq,
    const float* __restrict__ Pmin, const float* __restrict__ Pmax,
    const int* __restrict__ gstart,
    const float* __restrict__ g1, const float* __restrict__ be1,
    const float* __restrict__ g2, const float* __restrict__ be2,
    float* __restrict__ Hg) {
    int t = blockIdx.x;          // column 0..D3-1
    int g = threadIdx.x;         // graph 0..63
    int f = t / DD, c = t - f * DD;  // f: 0=avg 1=sum 2=max (block-uniform)
    float Sg = 0.f, Qg = 0.f;
#pragma unroll
    for (int s = 0; s < PS; s++) {
        Sg += Psum[(g * PS + s) * DD + c];
        Qg += Psq[(g * PS + s) * DD + c];
    }
    float S = Sg, Q = Qg;
    for (int off = 32; off > 0; off >>= 1) {
        S += __shfl_xor(S, off);
        Q += __shfl_xor(Q, off);
    }
    float mu = S * (1.f / (float)NN);
    float var = Q * (1.f / (float)NN) - mu * mu;
    float sc = g1[c] * rsqrtf(var + EPSB);
    float bb = be1[c];
    float v;
    if (f == 2) {
        float mx = -INFINITY, mn = INFINITY;
#pragma unroll
        for (int s = 0; s < PS; s++) {
            mx = fmaxf(mx, Pmax[(g * PS + s) * DD + c]);
            mn = fminf(mn, Pmin[(g * PS + s) * DD + c]);
        }
        float raw = (sc >= 0.f) ? mx : mn;
        v = sc * (raw - mu) + bb;
    } else {
        float nf = (float)(gstart[g + 1] - gstart[g]);
        float hsum = sc * (Sg - nf * mu) + nf * bb;
        v = (f == 0) ? hsum / fmaxf(nf, 1.f) : hsum;
    }
    float s2 = v, ss2 = v * v;
    for (int off = 32; off > 0; off >>= 1) {
        s2 += __shfl_xor(s2, off);
        ss2 += __shfl_xor(ss2, off);
    }
    float m2 = s2 * (1.f / (float)GG);
    float var2 = ss2 * (1.f / (float)GG) - m2 * m2;
    float sc2 = g2[t] * rsqrtf(var2 + EPSB);
    Hg[g * D3 + t] = sc2 * (v - m2) + be2[t];
}

// ------ funnel head + log_softmax, ONE graph per block (64 blocks) ----------
__global__ __launch_bounds__(F1) void funnel_kernel(const float* __restrict__ Hg,
    const float* __restrict__ Wp1, const float* __restrict__ b1,
    const float* __restrict__ Wp2, const float* __restrict__ b2,
    const float* __restrict__ w3, const float* __restrict__ b3,
    float* __restrict__ out) {
    __shared__ float hg[D3];
    __shared__ float x1[F1];
    __shared__ float x2[F2];
    __shared__ float lg[NCLS];
    __shared__ float s_lse;
    int g = blockIdx.x, t = threadIdx.x;
    for (int i = t; i < D3; i += F1) hg[i] = Hg[g * D3 + i];
    __syncthreads();
    {
        float a = b1[t];
        const float4* W4 = (const float4*)Wp1;
        for (int k4 = 0; k4 < D3 / 4; k4++) {
            float4 w = W4[k4 * F1 + t];                 // coalesced
            const float4 h = *(const float4*)&hg[k4 * 4]; // broadcast
            a += w.x * h.x + w.y * h.y + w.z * h.z + w.w * h.w;
        }
        x1[t] = fmaxf(a, 0.f);
    }
    __syncthreads();
    if (t < F2) {
        float a = b2[t];
        const float4* W4 = (const float4*)Wp2;
        for (int k4 = 0; k4 < F1 / 4; k4++) {
            float4 w = W4[k4 * F2 + t];                 // coalesced
            const float4 h = *(const float4*)&x1[k4 * 4]; // broadcast
            a += w.x * h.x + w.y * h.y + w.z * h.z + w.w * h.w;
        }
        x2[t] = fmaxf(a, 0.f);
    }
    __syncthreads();
    if (t < NCLS) {
        float a = b3[t];
        const float4* wr = (const float4*)&w3[t * F2];
        const float4* h4 = (const float4*)x2;
        for (int k = 0; k < F2 / 4; k++) {
            float4 w = wr[k], h = h4[k];
            a += w.x * h.x + w.y * h.y + w.z * h.z + w.w * h.w;
        }
        lg[t] = a;
    }
    __syncthreads();
    if (t == 0) {
        float m = lg[0];
        for (int i = 1; i < NCLS; i++) m = fmaxf(m, lg[i]);
        float se = 0.f;
        for (int i = 0; i < NCLS; i++) se += expf(lg[i] - m);
        s_lse = m + logf(se);
    }
    __syncthreads();
    if (t < NCLS) out[g * NCLS + t] = lg[t] - s_lse;
}

// ---------------- launcher ----------------

extern "C" void kernel_launch(void* const* d_in, const int* in_sizes, int n_in,
                              void* d_out, int out_size, void* d_ws, size_t ws_size,
                              hipStream_t stream) {
    (void)in_sizes; (void)n_in; (void)out_size; (void)ws_size;
    const float* x     = (const float*)d_in[0];
    const int*   ei    = (const int*)d_in[1];    // int32 on device (harness contract)
    const int*   batch = (const int*)d_in[2];
    const float* W     = (const float*)d_in[3];
    const float* b     = (const float*)d_in[4];
    const float* u     = (const float*)d_in[5];
    const float* g1    = (const float*)d_in[6];
    const float* be1   = (const float*)d_in[7];
    const float* g2    = (const float*)d_in[8];
    const float* be2   = (const float*)d_in[9];
    const float* w1    = (const float*)d_in[10];
    const float* b1    = (const float*)d_in[11];
    const float* w2    = (const float*)d_in[12];
    const float* b2    = (const float*)d_in[13];
    const float* w3    = (const float*)d_in[14];
    const float* b3    = (const float*)d_in[15];
    float* out = (float*)d_out;
    char*  ws  = (char*)d_ws;

    // ---- workspace layout (bytes), ~12 MB ----
    int*            gstart  = (int*)(ws + 0);            //     512 (65 ints)
    int*            rowptr  = (int*)(ws + 512);          //   33024
    int*            deg     = (int*)(ws + 33536);        //   32768
    float*          dinv    = (float*)(ws + 66304);      //   32768
    float*          sig     = (float*)(ws + 99072);      //     256
    float*          Wp      = (float*)(ws + 99328);      //  147456
    float*          Psum    = (float*)(ws + 246784);     //  393216 (GG*PS*DD)
    float*          Psq     = (float*)(ws + 640000);     //  393216
    float*          Pmin    = (float*)(ws + 1033216);    //  393216
    float*          Pmax    = (float*)(ws + 1426432);    //  393216
    float*          Hg      = (float*)(ws + 1819648);    //  147456
    unsigned short* csr_col = (unsigned short*)(ws + 1967104); // 524288
    float*          Wp1     = (float*)(ws + 2491392);    //  884736
    float*          Wp2     = (float*)(ws + 3376128);    //  294912
    int*            pcnt    = (int*)(ws + 3671040);      // 2097152
    float*          Hcat    = (float*)(ws + 5768192);    // 6291456 -> end 12059648

    prep_kernel<<<326 + NB, 1024, 0, stream>>>(W, u, w1, w2, batch, ei,
                                               sig, gstart, pcnt, Wp, Wp1, Wp2);
    offs_kernel<<<NN / 256, 256, 0, stream>>>(pcnt, deg, dinv);
    scatter_kernel<<<NB, 1024, 0, stream>>>(ei, deg, pcnt, rowptr, csr_col);
    // pass 1: read x [N,64], write Hcat col-block 1 (+ copy x into col-block 0)
    spmm_kernel<<<NN * 64 / 256, 256, 0, stream>>>(x, CIN, 0, rowptr, csr_col, dinv, Hcat, CIN, 1);
    // pass 2: read Hcat col-block 1 (strided), write Hcat col-block 2
    spmm_kernel<<<NN * 64 / 256, 256, 0, stream>>>(Hcat, DD, CIN, rowptr, csr_col, dinv, Hcat, 2 * CIN, 0);
    gemm_kernel<<<NN / 16, 192, 0, stream>>>(Hcat, Wp, b, sig);
    pool_kernel<<<GG * PS, 192, 0, stream>>>(Hcat, gstart, Psum, Psq, Pmin, Pmax);
    hg_kernel<<<D3, 64, 0, stream>>>(Psum, Psq, Pmin, Pmax, gstart, g1, be1, g2, be2, Hg);
    funnel_kernel<<<GG, F1, 0, stream>>>(Hg, Wp1, b1, Wp2, b2, w3, b3, out);
}